// Round 5
// baseline (255.235 us; speedup 1.0000x reference)
//
#include <hip/hip_runtime.h>
#include <hip/hip_bf16.h>
#include <stdint.h>

#define DEVFN static __device__ __forceinline__

typedef __attribute__((ext_vector_type(8))) short bf16x8;
typedef __attribute__((ext_vector_type(4))) short s16x4;
typedef __attribute__((ext_vector_type(4))) float f32x4;

static constexpr int TOK = 8192;       // B*N
static constexpr int DIM = 768;
static constexpr int HEADS = 8;
static constexpr int HD = 96;
static constexpr int EXPERTS = 24;
static constexpr int NQ = 2304;        // EXPERTS*HD
static constexpr int NQP = 2560;       // NQ + 192 (kv) + 64 (zero pad)
static constexpr float C2 = 0.14724484f;   // HD^-0.5 * log2(e)
static constexpr float THRRAW = 78.0f;     // defer-max threshold, raw-score units

// ---- workspace layout (bytes) ----
static constexpr size_t OFF_XB   = 0;          // x bf16 [8192][768]   (o aliases)
static constexpr size_t OFF_BT1  = 12582912;   // Bt1 bf16 [2560][768]
static constexpr size_t OFF_W2T  = 16515072;   // W2t bf16 [768][2304]
static constexpr size_t OFF_K    = 20054016;   // Kp packed bf16 [128 tiles][12][64][8]
static constexpr size_t OFF_VT   = 21626880;   // Vp packed bf16 [128 tiles][8][96][8]
static constexpr size_t OFF_GATE = 23199744;   // gates f32 [8192][8]
static constexpr size_t OFF_TOPI = 23461888;   // topi i32 [8192][8]
static constexpr size_t OFF_AUX  = 23724032;   // me[24], fe[24], z
static constexpr size_t OFF_ALLQ = 23724288;   // allq bf16 [8192][2560]

DEVFN short f2bf(float f){
  __hip_bfloat16 h = __float2bfloat16(f);
  return __builtin_bit_cast(short, h);
}
DEVFN float bf2f(short u){
  return __bfloat162float(__builtin_bit_cast(__hip_bfloat16, u));
}

DEVFN void gload16(const void* g, void* l){
  auto gp = reinterpret_cast<__attribute__((address_space(1))) unsigned int*>(
      reinterpret_cast<uintptr_t>(g));
  auto lp = reinterpret_cast<__attribute__((address_space(3))) unsigned int*>(
      reinterpret_cast<uintptr_t>(l));
  __builtin_amdgcn_global_load_lds(gp, lp, 16, 0, 0);
}

// ---------------- fused prep: casts / transposes ----------------
__global__ __launch_bounds__(256) void prep_kernel(const float* __restrict__ x,
                                                   const float* __restrict__ W1,
                                                   const float* __restrict__ Wkv,
                                                   const float* __restrict__ W2,
                                                   short* __restrict__ xb,
                                                   short* __restrict__ Bt1,
                                                   short* __restrict__ W2t){
  int bid = blockIdx.x, tid = threadIdx.x;
  if (bid < 6144){                                    // cast x -> bf16
    int i = bid*256 + tid;
    float4 v = ((const float4*)x)[i];
    s16x4 o4;
    o4[0] = f2bf(v.x); o4[1] = f2bf(v.y); o4[2] = f2bf(v.z); o4[3] = f2bf(v.w);
    *reinterpret_cast<s16x4*>(xb + (size_t)i*4) = o4;
  } else if (bid < 13056){                            // W1 -> Bt1[n][k]
    int i = (bid-6144)*256 + tid;                     // 24*768*96
    int e = i / (DIM*HD);
    int rem = i - e*(DIM*HD);
    int d = rem / HD, hh = rem - d*HD;
    Bt1[(size_t)(e*HD + hh)*DIM + d] = f2bf(W1[i]);
  } else if (bid < 13632){                            // Wkv -> Bt1 kv rows
    int i = (bid-13056)*256 + tid;                    // 768*192
    int d = i / 192, j = i - d*192;
    Bt1[(size_t)(NQ + j)*DIM + d] = f2bf(Wkv[i]);
  } else if (bid < 13824){                            // zero pad rows
    int i = (bid-13632)*256 + tid;                    // 64*768
    Bt1[(size_t)(NQ + 192)*DIM + i] = 0;
  } else {                                            // W2 -> W2t[c][e*96+h]
    int i = (bid-13824)*256 + tid;                    // 24*96*768
    int e = i / (HD*DIM);
    int rem = i - e*(HD*DIM);
    int hh = rem / DIM, c = rem - hh*DIM;
    W2t[(size_t)c*NQ + e*HD + hh] = f2bf(W2[i]);
  }
}

// ---------------- gating v2: one wave per token, lane-parallel top-k ----------------
__global__ __launch_bounds__(256) void gating_kernel(const float* __restrict__ x,
                                                     const float* __restrict__ Wg,
                                                     const int* __restrict__ task,
                                                     int* __restrict__ topi,
                                                     float* __restrict__ gates,
                                                     float* __restrict__ auxbuf){
  __shared__ __align__(16) float red[4][EXPERTS][68];
  __shared__ float lme[EXPERTS];
  __shared__ float lfr[EXPERTS];
  __shared__ float lz;
  int tid = threadIdx.x;
  int lane = tid & 63, w = tid >> 6;
  if (tid < EXPERTS){ lme[tid] = 0.f; lfr[tid] = 0.f; }
  if (tid == 0) lz = 0.f;
  __syncthreads();

  int token = blockIdx.x*4 + w;
  const float* Wt = Wg + (size_t)task[0]*DIM*EXPERTS;
  const float* xr = x + (size_t)token*DIM;

  // dot products: lane covers d = i*64+lane; weight row via 6 float4 loads
  float accv[EXPERTS];
#pragma unroll
  for (int e = 0; e < EXPERTS; ++e) accv[e] = 0.f;
#pragma unroll
  for (int i = 0; i < 12; ++i){
    int d = i*64 + lane;
    float xv = xr[d];
    const float4* wr4 = reinterpret_cast<const float4*>(Wt + (size_t)d*EXPERTS);
#pragma unroll
    for (int q = 0; q < 6; ++q){
      float4 wv = wr4[q];
      accv[q*4+0] = fmaf(xv, wv.x, accv[q*4+0]);
      accv[q*4+1] = fmaf(xv, wv.y, accv[q*4+1]);
      accv[q*4+2] = fmaf(xv, wv.z, accv[q*4+2]);
      accv[q*4+3] = fmaf(xv, wv.w, accv[q*4+3]);
    }
  }
  // transpose via LDS: lane e < 24 ends up owning logit[e]
#pragma unroll
  for (int e = 0; e < EXPERTS; ++e) red[w][e][lane] = accv[e];
  float v = -3.0e38f;
  if (lane < EXPERTS){
    const float4* rr = reinterpret_cast<const float4*>(&red[w][lane][0]);
    float s0 = 0.f, s1 = 0.f, s2 = 0.f, s3 = 0.f;
#pragma unroll
    for (int j = 0; j < 16; ++j){
      float4 t4 = rr[j];
      s0 += t4.x; s1 += t4.y; s2 += t4.z; s3 += t4.w;
    }
    v = (s0 + s1) + (s2 + s3);
  }

  // top-8 on logits (same order as probs); ties -> lowest index (lax.top_k)
  float mv = v; int mi = lane;
  int sel[8]; float pg[8];
  float mx = 0.f;
  bool selflag = false;
#pragma unroll
  for (int t = 0; t < 8; ++t){
    float cv = mv; int ci = mi;
#pragma unroll
    for (int d = 1; d < 64; d <<= 1){
      float ov = __shfl_xor(cv, d, 64);
      int   oi = __shfl_xor(ci, d, 64);
      bool take = (ov > cv) || (ov == cv && oi < ci);
      cv = take ? ov : cv;
      ci = take ? oi : ci;
    }
    sel[t] = ci;
    pg[t] = cv;
    if (t == 0) mx = cv;
    bool hit = (lane == ci);
    selflag = selflag || hit;
    mv = hit ? -3.0e38f : mv;
  }

  // softmax pieces (f32, matches reference ordering class)
  float p = (lane < EXPERTS) ? __expf(v - mx) : 0.f;
  float S = p;
#pragma unroll
  for (int d = 1; d < 64; d <<= 1) S += __shfl_xor(S, d, 64);
  float lse = mx + __logf(S);
  float Sinv = 1.f / S;
#pragma unroll
  for (int t = 0; t < 8; ++t) pg[t] = __expf(pg[t] - mx) * Sinv;   // probs of selected
  float denom = ((pg[0]+pg[1])+(pg[2]+pg[3])) + ((pg[4]+pg[5])+(pg[6]+pg[7])) + 1e-6f;
  float dinv = 1.f / denom;

  if (lane < EXPERTS){
    atomicAdd(&lme[lane], p * Sinv);
    if (selflag) atomicAdd(&lfr[lane], 1.f);
  }
  if (lane == 0){
    atomicAdd(&lz, lse*lse);
#pragma unroll
    for (int t = 0; t < 8; ++t){
      topi[token*HEADS + t]  = sel[t];
      gates[token*HEADS + t] = pg[t]*dinv;
    }
  }
  __syncthreads();
  if (tid < EXPERTS) atomicAdd(&auxbuf[tid], lme[tid]);
  else if (tid >= 32 && tid < 32+EXPERTS) atomicAdd(&auxbuf[EXPERTS + tid-32], lfr[tid-32]);
  else if (tid == 63) atomicAdd(&auxbuf[2*EXPERTS], lz);
}

__global__ void aux_final(const float* __restrict__ auxbuf, float* __restrict__ outa){
  if (threadIdx.x != 0 || blockIdx.x != 0) return;
  float ms = 0.f, fs = 0.f;
  for (int e=0;e<EXPERTS;++e){ ms += auxbuf[e]; fs += auxbuf[EXPERTS+e]; }
  float sw = 0.f;
  for (int e=0;e<EXPERTS;++e) sw += (auxbuf[e]/ms)*(auxbuf[EXPERTS+e]/fs);
  sw *= (float)EXPERTS;
  float z = auxbuf[2*EXPERTS] / (float)TOK;
  outa[0] = 0.1f*sw + 0.001f*z;
}

// ---------------- bf16 MFMA GEMM: 128x128 tile, XCD swizzle, T2 LDS swizzle ----------------
template<bool OUT_BF16>
__global__ __launch_bounds__(256) void gemm_bt(const short* __restrict__ A,
                                               const short* __restrict__ Bt,
                                               void* __restrict__ Cout,
                                               int M, int N, int K){
  __shared__ short As[128*64];
  __shared__ short Bs[128*64];
  int nwg = gridDim.x*gridDim.y;
  int orig = blockIdx.y*gridDim.x + blockIdx.x;
  int cpx = nwg >> 3;
  int swz = (orig & 7)*cpx + (orig >> 3);   // requires nwg % 8 == 0
  int bx = swz % gridDim.x, by = swz / gridDim.x;

  int tid = threadIdx.x;
  int lane = tid & 63, w = tid >> 6;
  int wr = w >> 1, wc = w & 1;
  int l15 = lane & 15, lg = lane >> 4;
  int m0 = by * 128, n0 = bx * 128;

  f32x4 acc[4][4] = {};

  for (int k0 = 0; k0 < K; k0 += 64){
#pragma unroll
    for (int it = 0; it < 4; ++it){
      int c = it*256 + tid;
      int row = c >> 3, cc = c & 7;
      int csrc = cc ^ (row & 7);            // pre-swizzled source chunk
      gload16(A  + (size_t)(m0+row)*K + k0 + csrc*8, (char*)As + (size_t)c*16);
      gload16(Bt + (size_t)(n0+row)*K + k0 + csrc*8, (char*)Bs + (size_t)c*16);
    }
    __syncthreads();
#pragma unroll
    for (int kk = 0; kk < 2; ++kk){
      bf16x8 af[4], bfr[4];
      int jp = (kk*4 + lg) ^ (l15 & 7);     // phys chunk for logical kk*4+lg
#pragma unroll
      for (int m = 0; m < 4; ++m)
        af[m] = *reinterpret_cast<const bf16x8*>(&As[(wr*64 + m*16 + l15)*64 + jp*8]);
#pragma unroll
      for (int n = 0; n < 4; ++n)
        bfr[n] = *reinterpret_cast<const bf16x8*>(&Bs[(wc*64 + n*16 + l15)*64 + jp*8]);
#pragma unroll
      for (int m = 0; m < 4; ++m)
#pragma unroll
        for (int n = 0; n < 4; ++n)
          acc[m][n] = __builtin_amdgcn_mfma_f32_16x16x32_bf16(af[m], bfr[n], acc[m][n], 0, 0, 0);
    }
    __syncthreads();
  }
#pragma unroll
  for (int m = 0; m < 4; ++m)
#pragma unroll
    for (int n = 0; n < 4; ++n){
      int rbase = m0 + wr*64 + m*16 + lg*4;
      int col   = n0 + wc*64 + n*16 + l15;
#pragma unroll
      for (int r = 0; r < 4; ++r){
        float v = acc[m][n][r];
        size_t idx = (size_t)(rbase + r)*N + col;
        if constexpr (OUT_BF16) ((short*)Cout)[idx] = f2bf(v);
        else                    ((float*)Cout)[idx] = v;
      }
    }
}

// ---------------- GEMM2 fused: dbuf LDS + T14 async gather pipeline ----------------
// out = mixed(gated o, topi) @ W2. A gathered to regs early, ds_written late;
// B prefetched via gload_lds across the single per-iter barrier. BK=64.
__global__ __launch_bounds__(256) void gemm2_fused(const short* __restrict__ o,
                                                   const int* __restrict__ topi,
                                                   const short* __restrict__ W2t,
                                                   float* __restrict__ out){
  __shared__ short As[2][128*64];
  __shared__ short Bs[2][64*64];
  __shared__ signed char hmap[128][24];
  int nwg = gridDim.x*gridDim.y;
  int orig = blockIdx.y*gridDim.x + blockIdx.x;
  int cpx = nwg >> 3;
  int swz = (orig & 7)*cpx + (orig >> 3);   // 12*64=768, %8==0
  int bx = swz % gridDim.x, by = swz / gridDim.x;

  int tid = threadIdx.x;
  int lane = tid & 63, w = tid >> 6;
  int l15 = lane & 15, lg = lane >> 4;
  int m0 = by * 128, n0 = bx * 64;

  int* hm32 = (int*)&hmap[0][0];
  for (int i = tid; i < 768; i += 256) hm32[i] = -1;   // all bytes 0xFF
  __syncthreads();
  for (int i = tid; i < 128*8; i += 256){
    int row = i >> 3, hh = i & 7;
    int e = topi[(size_t)(m0+row)*HEADS + hh];
    hmap[row][e] = (signed char)hh;
  }
  __syncthreads();

  // per-thread A-gather invariants: 4 chunks (row, cc)
  int arow[4], accv[4];
  size_t arbase[4];
#pragma unroll
  for (int it = 0; it < 4; ++it){
    int c = it*256 + tid;
    arow[it] = c >> 3; accv[it] = c & 7;
    arbase[it] = (size_t)(m0 + arow[it])*DIM;
  }

  f32x4 acc[2][4] = {};
  bf16x8 areg[4];

  // ---- staging helpers (inline) ----
#define STAGE_A(kt, dst)                                                     \
  {                                                                          \
    _Pragma("unroll")                                                        \
    for (int it = 0; it < 4; ++it){                                          \
      unsigned kc = (unsigned)((kt)*8 + accv[it]);                           \
      unsigned e = kc / 12u;                                                 \
      unsigned dc = kc - e*12u;                                              \
      int hh = hmap[arow[it]][e];                                            \
      bf16x8 av = {};                                                        \
      if (hh >= 0)                                                           \
        av = *reinterpret_cast<const bf16x8*>(o + arbase[it] + hh*HD + dc*8);\
      dst[it] = av;                                                          \
    }                                                                        \
  }
#define WRITE_A(buf, src)                                                    \
  {                                                                          \
    _Pragma("unroll")                                                        \
    for (int it = 0; it < 4; ++it)                                           \
      *reinterpret_cast<bf16x8*>(                                            \
        &As[buf][arow[it]*64 + ((accv[it] ^ (arow[it] & 7)))*8]) = src[it];  \
  }
#define STAGE_B(kt, buf)                                                     \
  {                                                                          \
    _Pragma("unroll")                                                        \
    for (int it = 0; it < 2; ++it){                                          \
      int c = it*256 + tid;                                                  \
      int row = c >> 3, cc = c & 7;                                          \
      int csrc = cc ^ (row & 7);                                             \
      gload16(W2t + (size_t)(n0+row)*NQ + (kt)*64 + csrc*8,                  \
              (char*)&Bs[buf][0] + (size_t)c*16);                            \
    }                                                                        \
  }

  // prologue
  STAGE_A(0, areg);
  STAGE_B(0, 0);
  WRITE_A(0, areg);
  __syncthreads();

  for (int kt = 0; kt < 36; ++kt){
    int buf = kt & 1;
    bf16x8 anext[4];
    if (kt < 35){
      STAGE_A(kt+1, anext);       // global loads in flight under MFMA
      STAGE_B(kt+1, buf^1);       // gload_lds in flight across barrier
    }
#pragma unroll
    for (int kk = 0; kk < 2; ++kk){
      int jp = (kk*4 + lg) ^ (l15 & 7);
      bf16x8 af[2], bfr[4];
#pragma unroll
      for (int m = 0; m < 2; ++m)
        af[m] = *reinterpret_cast<const bf16x8*>(&As[buf][(w*32 + m*16 + l15)*64 + jp*8]);
#pragma unroll
      for (int n = 0; n < 4; ++n)
        bfr[n] = *reinterpret_cast<const bf16x8*>(&Bs[buf][(n*16 + l15)*64 + jp*8]);
#pragma unroll
      for (int m = 0; m < 2; ++m)
#pragma unroll
        for (int n = 0; n < 4; ++n)
          acc[m][n] = __builtin_amdgcn_mfma_f32_16x16x32_bf16(af[m], bfr[n], acc[m][n], 0, 0, 0);
    }
    if (kt < 35) WRITE_A(buf^1, anext);
    __syncthreads();
  }
#undef STAGE_A
#undef WRITE_A
#undef STAGE_B

#pragma unroll
  for (int m = 0; m < 2; ++m)
#pragma unroll
    for (int n = 0; n < 4; ++n){
      int rbase = m0 + w*32 + m*16 + lg*4;
      int col   = n0 + n*16 + l15;
#pragma unroll
      for (int r = 0; r < 4; ++r)
        out[(size_t)(rbase + r)*DIM + col] = acc[m][n][r];
    }
}

// ---------------- split kv: bias + repack into fragment-chunk order ----------------
__global__ __launch_bounds__(256) void split_kv_tile(const short* __restrict__ allq,
                                                     const float* __restrict__ bkv,
                                                     short* __restrict__ Kp,
                                                     short* __restrict__ Vp){
  __shared__ short kv[64*192];
  int bt = blockIdx.x;                 // b*16 + nt
  int b = bt >> 4;
  int tid = threadIdx.x;
#pragma unroll
  for (int it = 0; it < 6; ++it){
    int c = it*256 + tid;              // 1536 chunks of 16B
    int j = c / 24, cc = c - j*24;
    int token = b*1024 + (bt & 15)*64 + j;
    gload16(allq + (size_t)token*NQP + NQ + cc*8, (char*)kv + (size_t)c*16);
  }
  __syncthreads();
#pragma unroll
  for (int it = 0; it < 3; ++it){
    int c = it*256 + tid;              // 768 K chunks
    int kc = c >> 6, j = c & 63;
    bf16x8 v = *reinterpret_cast<const bf16x8*>(&kv[j*192 + kc*8]);
    bf16x8 o8;
#pragma unroll
    for (int e = 0; e < 8; ++e) o8[e] = f2bf(bf2f(v[e]) + bkv[kc*8 + e]);
    *reinterpret_cast<bf16x8*>(Kp + ((size_t)bt*768 + c)*8) = o8;
  }
#pragma unroll
  for (int it = 0; it < 3; ++it){
    int c = it*256 + tid;              // 768 V chunks
    int kc = c / 96, hd = c - kc*96;
    float bias = bkv[96 + hd];
    bf16x8 o8;
#pragma unroll
    for (int e = 0; e < 8; ++e) o8[e] = f2bf(bf2f(kv[(kc*8 + e)*192 + 96 + hd]) + bias);
    *reinterpret_cast<bf16x8*>(Vp + ((size_t)bt*768 + c)*8) = o8;
  }
}

// ---------------- flash attention: 32 q-rows/wave, dbuf staging, lazy softmax, gate-folded ----------------
__global__ __launch_bounds__(256, 2) void attn_fwd(const short* __restrict__ allq,
                                                   const int* __restrict__ topi,
                                                   const float* __restrict__ gates,
                                                   const short* __restrict__ Kp,
                                                   const short* __restrict__ Vp,
                                                   short* __restrict__ o){
  __shared__ short Klds[2][768*8];
  __shared__ short Vlds[2][768*8];
  __shared__ short Plds[4][16*72];
  int qt = blockIdx.x, bh = blockIdx.y;        // qt in [0,8): 128 q-rows per block
  int b = bh >> 3, h = bh & 7;
  int tid = threadIdx.x;
  int lane = tid & 63, w = tid >> 6;
  int l15 = lane & 15, lg = lane >> 4;

  bf16x8 qf[2][3];
  int tok0 = b*1024 + qt*128 + w*32;
#pragma unroll
  for (int qm = 0; qm < 2; ++qm){
    int token = tok0 + qm*16 + l15;
    int qe = topi[token*HEADS + h];
    const short* qp = allq + (size_t)token*NQP + qe*HD;
#pragma unroll
    for (int t = 0; t < 3; ++t)
      qf[qm][t] = *reinterpret_cast<const bf16x8*>(qp + t*32 + lg*8);
  }

  f32x4 Oacc[2][6] = {};
  float mrun[2][4], lrun[2][4];
#pragma unroll
  for (int qm = 0; qm < 2; ++qm)
#pragma unroll
    for (int r = 0; r < 4; ++r){ mrun[qm][r] = -1.0e30f; lrun[qm][r] = 0.f; }

  const short* kb = Kp + (size_t)b*16*768*8;
  const short* vb = Vp + (size_t)b*16*768*8;

#pragma unroll
  for (int it = 0; it < 3; ++it){
    int c = it*256 + tid;
    gload16(kb + (size_t)c*8, (char*)&Klds[0][0] + (size_t)c*16);
    gload16(vb + (size_t)c*8, (char*)&Vlds[0][0] + (size_t)c*16);
  }
  __syncthreads();

  int cur = 0;
  for (int nt = 0; nt < 16; ++nt){
    if (nt < 15){
      const short* kn = kb + (size_t)(nt+1)*768*8;
      const short* vn = vb + (size_t)(nt+1)*768*8;
#pragma unroll
      for (int it = 0; it < 3; ++it){
        int c = it*256 + tid;
        gload16(kn + (size_t)c*8, (char*)&Klds[cur^1][0] + (size_t)c*16);
        gload16(vn + (size_t)c*8, (char*)&Vlds[cur^1][0] + (size_t)c*16);
      }
    }

    f32x4 sa[2][4];
    __builtin_amdgcn_s_setprio(1);
#pragma unroll
    for (int ct = 0; ct < 4; ++ct){
      bf16x8 kf[3];
#pragma unroll
      for (int t = 0; t < 3; ++t)
        kf[t] = *reinterpret_cast<const bf16x8*>(&Klds[cur][((t*4+lg)*64 + ct*16 + l15)*8]);
#pragma unroll
      for (int qm = 0; qm < 2; ++qm){
        f32x4 a = {};
#pragma unroll
        for (int t = 0; t < 3; ++t)
          a = __builtin_amdgcn_mfma_f32_16x16x32_bf16(qf[qm][t], kf[t], a, 0, 0, 0);
        sa[qm][ct] = a;
      }
    }
    __builtin_amdgcn_s_setprio(0);

    float pmax[2][4];
    bool need = false;
#pragma unroll
    for (int qm = 0; qm < 2; ++qm)
#pragma unroll
      for (int r = 0; r < 4; ++r){
        pmax[qm][r] = fmaxf(fmaxf(sa[qm][0][r], sa[qm][1][r]),
                            fmaxf(sa[qm][2][r], sa[qm][3][r]));
        need = need || (pmax[qm][r] > mrun[qm][r] + THRRAW);
      }
    if (__any(need)){
#pragma unroll
      for (int qm = 0; qm < 2; ++qm)
#pragma unroll
        for (int r = 0; r < 4; ++r){
          float mx = pmax[qm][r];
#pragma unroll
          for (int d = 1; d < 16; d <<= 1) mx = fmaxf(mx, __shfl_xor(mx, d, 64));
          float mnew = fmaxf(mrun[qm][r], mx);
          float al = exp2f((mrun[qm][r] - mnew)*C2);
          lrun[qm][r] *= al;
#pragma unroll
          for (int dt = 0; dt < 6; ++dt) Oacc[qm][dt][r] *= al;
          mrun[qm][r] = mnew;
        }
    }

#pragma unroll
    for (int qm = 0; qm < 2; ++qm)
#pragma unroll
      for (int r = 0; r < 4; ++r){
        float mc = mrun[qm][r]*C2;
        float s = 0.f;
#pragma unroll
        for (int ct = 0; ct < 4; ++ct){
          float p = exp2f(fmaf(sa[qm][ct][r], C2, -mc));
          sa[qm][ct][r] = p; s += p;
        }
        lrun[qm][r] += s;
      }

    bf16x8 vf[2][6];
#pragma unroll
    for (int ct = 0; ct < 4; ++ct)
#pragma unroll
      for (int r = 0; r < 4; ++r)
        Plds[w][(lg*4 + r)*72 + ct*16 + l15] = f2bf(sa[0][ct][r]);
    __builtin_amdgcn_s_setprio(1);
#pragma unroll
    for (int ks = 0; ks < 2; ++ks){
      bf16x8 pa = *reinterpret_cast<const bf16x8*>(&Plds[w][l15*72 + ks*32 + lg*8]);
#pragma unroll
      for (int dt = 0; dt < 6; ++dt){
        vf[ks][dt] = *reinterpret_cast<const bf16x8*>(&Vlds[cur][((ks*4+lg)*96 + dt*16 + l15)*8]);
        Oacc[0][dt] = __builtin_amdgcn_mfma_f32_16x16x32_bf16(pa, vf[ks][dt], Oacc[0][dt], 0, 0, 0);
      }
    }
    __builtin_amdgcn_s_setprio(0);
#pragma unroll
    for (int ct = 0; ct < 4; ++ct)
#pragma unroll
      for (int r = 0; r < 4; ++r)
        Plds[w][(lg*4 + r)*72 + ct*16 + l15] = f2bf(sa[1][ct][r]);
    __builtin_amdgcn_s_setprio(1);
#pragma unroll
    for (int ks = 0; ks < 2; ++ks){
      bf16x8 pa = *reinterpret_cast<const bf16x8*>(&Plds[w][l15*72 + ks*32 + lg*8]);
#pragma unroll
      for (int dt = 0; dt < 6; ++dt)
        Oacc[1][dt] = __builtin_amdgcn_mfma_f32_16x16x32_bf16(pa, vf[ks][dt], Oacc[1][dt], 0, 0, 0);
    }
    __builtin_amdgcn_s_setprio(0);

    __syncthreads();
    cur ^= 1;
  }

  // epilogue: reduce l once; fold gate so o = gate * softmax(QK)V
#pragma unroll
  for (int qm = 0; qm < 2; ++qm)
#pragma unroll
    for (int r = 0; r < 4; ++r){
      float l = lrun[qm][r];
#pragma unroll
      for (int d = 1; d < 16; d <<= 1) l += __shfl_xor(l, d, 64);
      int token = tok0 + qm*16 + lg*4 + r;
      float inv = gates[token*HEADS + h] / l;
#pragma unroll
      for (int dt = 0; dt < 6; ++dt)
        o[(size_t)token*DIM + h*HD + dt*16 + l15] = f2bf(Oacc[qm][dt][r]*inv);
    }
}

// ---------------- launch ----------------
extern "C" void kernel_launch(void* const* d_in, const int* in_sizes, int n_in,
                              void* d_out, int out_size, void* d_ws, size_t ws_size,
                              hipStream_t stream) {
  (void)in_sizes; (void)n_in; (void)out_size; (void)ws_size;
  const float* x    = (const float*)d_in[0];
  const float* Wg   = (const float*)d_in[1];
  const float* W1   = (const float*)d_in[2];
  const float* W2   = (const float*)d_in[3];
  const float* Wkv  = (const float*)d_in[4];
  const float* bkv  = (const float*)d_in[5];
  const int*   task = (const int*)d_in[6];

  char* ws = (char*)d_ws;
  short* xb    = (short*)(ws + OFF_XB);
  short* o     = (short*)(ws + OFF_XB);    // alias: xb dead after GEMM1
  short* Bt1   = (short*)(ws + OFF_BT1);
  short* W2t   = (short*)(ws + OFF_W2T);
  short* Kp    = (short*)(ws + OFF_K);
  short* Vp    = (short*)(ws + OFF_VT);
  float* gates = (float*)(ws + OFF_GATE);
  int*   topi  = (int*)(ws + OFF_TOPI);
  float* aux   = (float*)(ws + OFF_AUX);
  short* allq  = (short*)(ws + OFF_ALLQ);
  float* out   = (float*)d_out;

  hipMemsetAsync(aux, 0, 256, stream);
  prep_kernel  <<<20736, 256, 0, stream>>>(x, W1, Wkv, W2, xb, Bt1, W2t);
  gating_kernel<<<TOK/4, 256, 0, stream>>>(x, Wg, task, topi, gates, aux);
  aux_final    <<<1, 64, 0, stream>>>(aux, out + (size_t)TOK*DIM);
  // all_q (+ kv columns): [8192,768] x [768,2560]
  gemm_bt<true><<<dim3(NQP/128, TOK/128), 256, 0, stream>>>(xb, Bt1, allq, TOK, NQP, DIM);
  split_kv_tile<<<128, 256, 0, stream>>>(allq, bkv, Kp, Vp);
  attn_fwd     <<<dim3(8, 64), 256, 0, stream>>>(allq, topi, gates, Kp, Vp, o);
  // out = mixed(gated o) @ W2 : [8192,2304] x [2304,768], A built in-kernel
  gemm2_fused  <<<dim3(DIM/64, TOK/128), 256, 0, stream>>>(o, topi, W2t, out);
}

// Round 6
// 223.551 us; speedup vs baseline: 1.1417x; 1.1417x over previous
//
#include <hip/hip_runtime.h>
#include <hip/hip_bf16.h>
#include <stdint.h>

#define DEVFN static __device__ __forceinline__

typedef __attribute__((ext_vector_type(8))) short bf16x8;
typedef __attribute__((ext_vector_type(4))) short s16x4;
typedef __attribute__((ext_vector_type(4))) float f32x4;

static constexpr int TOK = 8192;       // B*N
static constexpr int DIM = 768;
static constexpr int HEADS = 8;
static constexpr int HD = 96;
static constexpr int EXPERTS = 24;
static constexpr int NQ = 2304;        // EXPERTS*HD
static constexpr int NQP = 2560;       // NQ + 192 (kv) + 64 (zero pad)
static constexpr float C2 = 0.14724484f;   // HD^-0.5 * log2(e)
static constexpr float THRRAW = 78.0f;     // defer-max threshold, raw-score units

// ---- workspace layout (bytes) ----
static constexpr size_t OFF_XB   = 0;          // x bf16 [8192][768]   (o aliases)
static constexpr size_t OFF_BT1  = 12582912;   // Bt1 bf16 [2560][768]
static constexpr size_t OFF_W2T  = 16515072;   // W2t bf16 [768][2304]
static constexpr size_t OFF_K    = 20054016;   // Kp packed bf16 [128 tiles][12][64][8]
static constexpr size_t OFF_VT   = 21626880;   // Vp packed bf16 [128 tiles][8][96][8]
static constexpr size_t OFF_GATE = 23199744;   // gates f32 [8192][8]
static constexpr size_t OFF_TOPI = 23461888;   // topi i32 [8192][8]
static constexpr size_t OFF_AUX  = 23724032;   // me[24], fe[24], z
static constexpr size_t OFF_ALLQ = 23724288;   // allq bf16 [8192][2560]

DEVFN short f2bf(float f){
  __hip_bfloat16 h = __float2bfloat16(f);
  return __builtin_bit_cast(short, h);
}
DEVFN float bf2f(short u){
  return __bfloat162float(__builtin_bit_cast(__hip_bfloat16, u));
}

DEVFN void gload16(const void* g, void* l){
  auto gp = reinterpret_cast<__attribute__((address_space(1))) unsigned int*>(
      reinterpret_cast<uintptr_t>(g));
  auto lp = reinterpret_cast<__attribute__((address_space(3))) unsigned int*>(
      reinterpret_cast<uintptr_t>(l));
  __builtin_amdgcn_global_load_lds(gp, lp, 16, 0, 0);
}

// ---------------- fused prep: casts / transposes ----------------
__global__ __launch_bounds__(256) void prep_kernel(const float* __restrict__ x,
                                                   const float* __restrict__ W1,
                                                   const float* __restrict__ Wkv,
                                                   const float* __restrict__ W2,
                                                   short* __restrict__ xb,
                                                   short* __restrict__ Bt1,
                                                   short* __restrict__ W2t){
  int bid = blockIdx.x, tid = threadIdx.x;
  if (bid < 6144){                                    // cast x -> bf16
    int i = bid*256 + tid;
    float4 v = ((const float4*)x)[i];
    s16x4 o4;
    o4[0] = f2bf(v.x); o4[1] = f2bf(v.y); o4[2] = f2bf(v.z); o4[3] = f2bf(v.w);
    *reinterpret_cast<s16x4*>(xb + (size_t)i*4) = o4;
  } else if (bid < 13056){                            // W1 -> Bt1[n][k]
    int i = (bid-6144)*256 + tid;                     // 24*768*96
    int e = i / (DIM*HD);
    int rem = i - e*(DIM*HD);
    int d = rem / HD, hh = rem - d*HD;
    Bt1[(size_t)(e*HD + hh)*DIM + d] = f2bf(W1[i]);
  } else if (bid < 13632){                            // Wkv -> Bt1 kv rows
    int i = (bid-13056)*256 + tid;                    // 768*192
    int d = i / 192, j = i - d*192;
    Bt1[(size_t)(NQ + j)*DIM + d] = f2bf(Wkv[i]);
  } else if (bid < 13824){                            // zero pad rows
    int i = (bid-13632)*256 + tid;                    // 64*768
    Bt1[(size_t)(NQ + 192)*DIM + i] = 0;
  } else {                                            // W2 -> W2t[c][e*96+h]
    int i = (bid-13824)*256 + tid;                    // 24*96*768
    int e = i / (HD*DIM);
    int rem = i - e*(HD*DIM);
    int hh = rem / DIM, c = rem - hh*DIM;
    W2t[(size_t)c*NQ + e*HD + hh] = f2bf(W2[i]);
  }
}

// ---------------- gating v3: LDS-staged W, transaction-clean, f32 ----------------
// 512 blocks x 16 tokens. Wave = 4 tokens (16-lane groups). W staged per K-half
// into [384][25]-padded LDS (pad-25: lanes j=0..15 at row stride 2 hit 16 distinct
// banks; token groups broadcast). x read once, coalesced float2. Top-8 serial per
// token, redundant across the 16 lanes of its group (no divergence).
__global__ __launch_bounds__(256) void gating_kernel(const float* __restrict__ x,
                                                     const float* __restrict__ Wg,
                                                     const int* __restrict__ task,
                                                     int* __restrict__ topi,
                                                     float* __restrict__ gates,
                                                     float* __restrict__ auxbuf){
  __shared__ float Wl[384*25];        // 38400 B
  __shared__ float part[16][25];      // K-half-0 logits
  __shared__ float lme[EXPERTS];
  __shared__ float lfr[EXPERTS];
  __shared__ float lz;
  int tid = threadIdx.x;
  int lane = tid & 63, w = tid >> 6;
  int g = lane >> 4, j = lane & 15;
  if (tid < EXPERTS){ lme[tid] = 0.f; lfr[tid] = 0.f; }
  if (tid == 0) lz = 0.f;

  int tokloc = w*4 + g;
  int token = blockIdx.x*16 + tokloc;
  const float* Wt = Wg + (size_t)task[0]*(DIM*EXPERTS);
  const float* xr = x + (size_t)token*DIM;

  float acc[EXPERTS];
#pragma unroll
  for (int e = 0; e < EXPERTS; ++e) acc[e] = 0.f;

  for (int kh = 0; kh < 2; ++kh){
    __syncthreads();                 // waves done with previous Wl (and lme init)
    // stage K-half: rows [kh*384, kh*384+384) -> Wl[d][25], coalesced float4 reads
    for (int idx = tid; idx < 384*6; idx += 256){
      int d = idx / 6, q = idx - d*6;
      float4 w4 = *reinterpret_cast<const float4*>(Wt + (size_t)(kh*384 + d)*EXPERTS + q*4);
      float* dst = &Wl[d*25 + q*4];
      dst[0] = w4.x; dst[1] = w4.y; dst[2] = w4.z; dst[3] = w4.w;
    }
    __syncthreads();

#pragma unroll 2
    for (int i = 0; i < 12; ++i){
      int d = i*32 + j*2;
      float2 xv = *reinterpret_cast<const float2*>(xr + kh*384 + d);
      const float* w0 = &Wl[d*25];
#pragma unroll
      for (int e = 0; e < EXPERTS; ++e)
        acc[e] = fmaf(xv.x, w0[e], fmaf(xv.y, w0[25 + e], acc[e]));
    }

    if (kh == 0){
      // reduce K-half-0 within the 16-lane group, stash, reset
#pragma unroll
      for (int e = 0; e < EXPERTS; ++e){
        float v = acc[e];
#pragma unroll
        for (int m = 1; m < 16; m <<= 1) v += __shfl_xor(v, m, 64);
        acc[e] = v;
      }
      part[tokloc][j] = acc[j];
      if (j < 8) part[tokloc][16 + j] = acc[16 + j];
#pragma unroll
      for (int e = 0; e < EXPERTS; ++e) acc[e] = 0.f;
    }
  }
  // final reduce + add stashed partial -> full logits in every lane of the group
#pragma unroll
  for (int e = 0; e < EXPERTS; ++e){
    float v = acc[e];
#pragma unroll
    for (int m = 1; m < 16; m <<= 1) v += __shfl_xor(v, m, 64);
    acc[e] = v + part[tokloc][e];
  }

  // top-8 (strict >, lowest index wins ties -> matches lax.top_k)
  float mx = acc[0];
#pragma unroll
  for (int e = 1; e < EXPERTS; ++e) mx = fmaxf(mx, acc[e]);
  unsigned selm = 0; int sel[8]; float sg[8];
#pragma unroll
  for (int t = 0; t < 8; ++t){
    float best = -3.0e38f; int bi = 0;
#pragma unroll
    for (int e = 0; e < EXPERTS; ++e){
      bool ok = !((selm>>e)&1u) && (acc[e] > best);
      best = ok ? acc[e] : best;
      bi   = ok ? e      : bi;
    }
    selm |= (1u<<bi); sel[t] = bi; sg[t] = best;
  }

  float S = 0.f;
#pragma unroll
  for (int e = 0; e < EXPERTS; ++e) S += __expf(acc[e] - mx);
  float lse = mx + __logf(S);
  float Sinv = 1.f/S;
  float gsum = 0.f;
#pragma unroll
  for (int t = 0; t < 8; ++t){ sg[t] = __expf(sg[t] - mx)*Sinv; gsum += sg[t]; }
  float dinv = 1.f/(gsum + 1e-6f);

  if (j == 0){
#pragma unroll
    for (int t = 0; t < 8; ++t){
      topi[token*HEADS + t]  = sel[t];
      gates[token*HEADS + t] = sg[t]*dinv;
    }
#pragma unroll
    for (int e = 0; e < EXPERTS; ++e) atomicAdd(&lme[e], __expf(acc[e] - mx)*Sinv);
#pragma unroll
    for (int t = 0; t < 8; ++t) atomicAdd(&lfr[sel[t]], 1.f);
    atomicAdd(&lz, lse*lse);
  }
  __syncthreads();
  if (tid < EXPERTS) atomicAdd(&auxbuf[tid], lme[tid]);
  else if (tid >= 32 && tid < 32+EXPERTS) atomicAdd(&auxbuf[EXPERTS + tid-32], lfr[tid-32]);
  else if (tid == 63) atomicAdd(&auxbuf[2*EXPERTS], lz);
}

__global__ void aux_final(const float* __restrict__ auxbuf, float* __restrict__ outa){
  if (threadIdx.x != 0 || blockIdx.x != 0) return;
  float ms = 0.f, fs = 0.f;
  for (int e=0;e<EXPERTS;++e){ ms += auxbuf[e]; fs += auxbuf[EXPERTS+e]; }
  float sw = 0.f;
  for (int e=0;e<EXPERTS;++e) sw += (auxbuf[e]/ms)*(auxbuf[EXPERTS+e]/fs);
  sw *= (float)EXPERTS;
  float z = auxbuf[2*EXPERTS] / (float)TOK;
  outa[0] = 0.1f*sw + 0.001f*z;
}

// ---------------- bf16 MFMA GEMM: 128x128 tile, XCD swizzle, T2 LDS swizzle ----------------
template<bool OUT_BF16>
__global__ __launch_bounds__(256) void gemm_bt(const short* __restrict__ A,
                                               const short* __restrict__ Bt,
                                               void* __restrict__ Cout,
                                               int M, int N, int K){
  __shared__ short As[128*64];
  __shared__ short Bs[128*64];
  int nwg = gridDim.x*gridDim.y;
  int orig = blockIdx.y*gridDim.x + blockIdx.x;
  int cpx = nwg >> 3;
  int swz = (orig & 7)*cpx + (orig >> 3);   // requires nwg % 8 == 0
  int bx = swz % gridDim.x, by = swz / gridDim.x;

  int tid = threadIdx.x;
  int lane = tid & 63, w = tid >> 6;
  int wr = w >> 1, wc = w & 1;
  int l15 = lane & 15, lg = lane >> 4;
  int m0 = by * 128, n0 = bx * 128;

  f32x4 acc[4][4] = {};

  for (int k0 = 0; k0 < K; k0 += 64){
#pragma unroll
    for (int it = 0; it < 4; ++it){
      int c = it*256 + tid;
      int row = c >> 3, cc = c & 7;
      int csrc = cc ^ (row & 7);            // pre-swizzled source chunk
      gload16(A  + (size_t)(m0+row)*K + k0 + csrc*8, (char*)As + (size_t)c*16);
      gload16(Bt + (size_t)(n0+row)*K + k0 + csrc*8, (char*)Bs + (size_t)c*16);
    }
    __syncthreads();
#pragma unroll
    for (int kk = 0; kk < 2; ++kk){
      bf16x8 af[4], bfr[4];
      int jp = (kk*4 + lg) ^ (l15 & 7);     // phys chunk for logical kk*4+lg
#pragma unroll
      for (int m = 0; m < 4; ++m)
        af[m] = *reinterpret_cast<const bf16x8*>(&As[(wr*64 + m*16 + l15)*64 + jp*8]);
#pragma unroll
      for (int n = 0; n < 4; ++n)
        bfr[n] = *reinterpret_cast<const bf16x8*>(&Bs[(wc*64 + n*16 + l15)*64 + jp*8]);
#pragma unroll
      for (int m = 0; m < 4; ++m)
#pragma unroll
        for (int n = 0; n < 4; ++n)
          acc[m][n] = __builtin_amdgcn_mfma_f32_16x16x32_bf16(af[m], bfr[n], acc[m][n], 0, 0, 0);
    }
    __syncthreads();
  }
#pragma unroll
  for (int m = 0; m < 4; ++m)
#pragma unroll
    for (int n = 0; n < 4; ++n){
      int rbase = m0 + wr*64 + m*16 + lg*4;
      int col   = n0 + wc*64 + n*16 + l15;
#pragma unroll
      for (int r = 0; r < 4; ++r){
        float v = acc[m][n][r];
        size_t idx = (size_t)(rbase + r)*N + col;
        if constexpr (OUT_BF16) ((short*)Cout)[idx] = f2bf(v);
        else                    ((float*)Cout)[idx] = v;
      }
    }
}

// ---------------- GEMM2 fused: dbuf LDS + T14 async gather pipeline ----------------
// out = mixed(gated o, topi) @ W2. A gathered to regs early, ds_written late;
// B prefetched via gload_lds across the single per-iter barrier. BK=64.
__global__ __launch_bounds__(256) void gemm2_fused(const short* __restrict__ o,
                                                   const int* __restrict__ topi,
                                                   const short* __restrict__ W2t,
                                                   float* __restrict__ out){
  __shared__ short As[2][128*64];
  __shared__ short Bs[2][64*64];
  __shared__ signed char hmap[128][24];
  int nwg = gridDim.x*gridDim.y;
  int orig = blockIdx.y*gridDim.x + blockIdx.x;
  int cpx = nwg >> 3;
  int swz = (orig & 7)*cpx + (orig >> 3);   // 12*64=768, %8==0
  int bx = swz % gridDim.x, by = swz / gridDim.x;

  int tid = threadIdx.x;
  int lane = tid & 63, w = tid >> 6;
  int l15 = lane & 15, lg = lane >> 4;
  int m0 = by * 128, n0 = bx * 64;

  int* hm32 = (int*)&hmap[0][0];
  for (int i = tid; i < 768; i += 256) hm32[i] = -1;   // all bytes 0xFF
  __syncthreads();
  for (int i = tid; i < 128*8; i += 256){
    int row = i >> 3, hh = i & 7;
    int e = topi[(size_t)(m0+row)*HEADS + hh];
    hmap[row][e] = (signed char)hh;
  }
  __syncthreads();

  // per-thread A-gather invariants: 4 chunks (row, cc)
  int arow[4], accv[4];
  size_t arbase[4];
#pragma unroll
  for (int it = 0; it < 4; ++it){
    int c = it*256 + tid;
    arow[it] = c >> 3; accv[it] = c & 7;
    arbase[it] = (size_t)(m0 + arow[it])*DIM;
  }

  f32x4 acc[2][4] = {};
  bf16x8 areg[4];

  // ---- staging helpers (inline) ----
#define STAGE_A(kt, dst)                                                     \
  {                                                                          \
    _Pragma("unroll")                                                        \
    for (int it = 0; it < 4; ++it){                                          \
      unsigned kc = (unsigned)((kt)*8 + accv[it]);                           \
      unsigned e = kc / 12u;                                                 \
      unsigned dc = kc - e*12u;                                              \
      int hh = hmap[arow[it]][e];                                            \
      bf16x8 av = {};                                                        \
      if (hh >= 0)                                                           \
        av = *reinterpret_cast<const bf16x8*>(o + arbase[it] + hh*HD + dc*8);\
      dst[it] = av;                                                          \
    }                                                                        \
  }
#define WRITE_A(buf, src)                                                    \
  {                                                                          \
    _Pragma("unroll")                                                        \
    for (int it = 0; it < 4; ++it)                                           \
      *reinterpret_cast<bf16x8*>(                                            \
        &As[buf][arow[it]*64 + ((accv[it] ^ (arow[it] & 7)))*8]) = src[it];  \
  }
#define STAGE_B(kt, buf)                                                     \
  {                                                                          \
    _Pragma("unroll")                                                        \
    for (int it = 0; it < 2; ++it){                                          \
      int c = it*256 + tid;                                                  \
      int row = c >> 3, cc = c & 7;                                          \
      int csrc = cc ^ (row & 7);                                             \
      gload16(W2t + (size_t)(n0+row)*NQ + (kt)*64 + csrc*8,                  \
              (char*)&Bs[buf][0] + (size_t)c*16);                            \
    }                                                                        \
  }

  // prologue
  STAGE_A(0, areg);
  STAGE_B(0, 0);
  WRITE_A(0, areg);
  __syncthreads();

  for (int kt = 0; kt < 36; ++kt){
    int buf = kt & 1;
    bf16x8 anext[4];
    if (kt < 35){
      STAGE_A(kt+1, anext);       // global loads in flight under MFMA
      STAGE_B(kt+1, buf^1);       // gload_lds in flight across barrier
    }
#pragma unroll
    for (int kk = 0; kk < 2; ++kk){
      int jp = (kk*4 + lg) ^ (l15 & 7);
      bf16x8 af[2], bfr[4];
#pragma unroll
      for (int m = 0; m < 2; ++m)
        af[m] = *reinterpret_cast<const bf16x8*>(&As[buf][(w*32 + m*16 + l15)*64 + jp*8]);
#pragma unroll
      for (int n = 0; n < 4; ++n)
        bfr[n] = *reinterpret_cast<const bf16x8*>(&Bs[buf][(n*16 + l15)*64 + jp*8]);
#pragma unroll
      for (int m = 0; m < 2; ++m)
#pragma unroll
        for (int n = 0; n < 4; ++n)
          acc[m][n] = __builtin_amdgcn_mfma_f32_16x16x32_bf16(af[m], bfr[n], acc[m][n], 0, 0, 0);
    }
    if (kt < 35) WRITE_A(buf^1, anext);
    __syncthreads();
  }
#undef STAGE_A
#undef WRITE_A
#undef STAGE_B

#pragma unroll
  for (int m = 0; m < 2; ++m)
#pragma unroll
    for (int n = 0; n < 4; ++n){
      int rbase = m0 + w*32 + m*16 + lg*4;
      int col   = n0 + n*16 + l15;
#pragma unroll
      for (int r = 0; r < 4; ++r)
        out[(size_t)(rbase + r)*DIM + col] = acc[m][n][r];
    }
}

// ---------------- split kv: bias + repack into fragment-chunk order ----------------
__global__ __launch_bounds__(256) void split_kv_tile(const short* __restrict__ allq,
                                                     const float* __restrict__ bkv,
                                                     short* __restrict__ Kp,
                                                     short* __restrict__ Vp){
  __shared__ short kv[64*192];
  int bt = blockIdx.x;                 // b*16 + nt
  int b = bt >> 4;
  int tid = threadIdx.x;
#pragma unroll
  for (int it = 0; it < 6; ++it){
    int c = it*256 + tid;              // 1536 chunks of 16B
    int j = c / 24, cc = c - j*24;
    int token = b*1024 + (bt & 15)*64 + j;
    gload16(allq + (size_t)token*NQP + NQ + cc*8, (char*)kv + (size_t)c*16);
  }
  __syncthreads();
#pragma unroll
  for (int it = 0; it < 3; ++it){
    int c = it*256 + tid;              // 768 K chunks
    int kc = c >> 6, j = c & 63;
    bf16x8 v = *reinterpret_cast<const bf16x8*>(&kv[j*192 + kc*8]);
    bf16x8 o8;
#pragma unroll
    for (int e = 0; e < 8; ++e) o8[e] = f2bf(bf2f(v[e]) + bkv[kc*8 + e]);
    *reinterpret_cast<bf16x8*>(Kp + ((size_t)bt*768 + c)*8) = o8;
  }
#pragma unroll
  for (int it = 0; it < 3; ++it){
    int c = it*256 + tid;              // 768 V chunks
    int kc = c / 96, hd = c - kc*96;
    float bias = bkv[96 + hd];
    bf16x8 o8;
#pragma unroll
    for (int e = 0; e < 8; ++e) o8[e] = f2bf(bf2f(kv[(kc*8 + e)*192 + 96 + hd]) + bias);
    *reinterpret_cast<bf16x8*>(Vp + ((size_t)bt*768 + c)*8) = o8;
  }
}

// ---------------- flash attention: 32 q-rows/wave, dbuf staging, lazy softmax, gate-folded ----------------
__global__ __launch_bounds__(256, 2) void attn_fwd(const short* __restrict__ allq,
                                                   const int* __restrict__ topi,
                                                   const float* __restrict__ gates,
                                                   const short* __restrict__ Kp,
                                                   const short* __restrict__ Vp,
                                                   short* __restrict__ o){
  __shared__ short Klds[2][768*8];
  __shared__ short Vlds[2][768*8];
  __shared__ short Plds[4][16*72];
  int qt = blockIdx.x, bh = blockIdx.y;        // qt in [0,8): 128 q-rows per block
  int b = bh >> 3, h = bh & 7;
  int tid = threadIdx.x;
  int lane = tid & 63, w = tid >> 6;
  int l15 = lane & 15, lg = lane >> 4;

  bf16x8 qf[2][3];
  int tok0 = b*1024 + qt*128 + w*32;
#pragma unroll
  for (int qm = 0; qm < 2; ++qm){
    int token = tok0 + qm*16 + l15;
    int qe = topi[token*HEADS + h];
    const short* qp = allq + (size_t)token*NQP + qe*HD;
#pragma unroll
    for (int t = 0; t < 3; ++t)
      qf[qm][t] = *reinterpret_cast<const bf16x8*>(qp + t*32 + lg*8);
  }

  f32x4 Oacc[2][6] = {};
  float mrun[2][4], lrun[2][4];
#pragma unroll
  for (int qm = 0; qm < 2; ++qm)
#pragma unroll
    for (int r = 0; r < 4; ++r){ mrun[qm][r] = -1.0e30f; lrun[qm][r] = 0.f; }

  const short* kb = Kp + (size_t)b*16*768*8;
  const short* vb = Vp + (size_t)b*16*768*8;

#pragma unroll
  for (int it = 0; it < 3; ++it){
    int c = it*256 + tid;
    gload16(kb + (size_t)c*8, (char*)&Klds[0][0] + (size_t)c*16);
    gload16(vb + (size_t)c*8, (char*)&Vlds[0][0] + (size_t)c*16);
  }
  __syncthreads();

  int cur = 0;
  for (int nt = 0; nt < 16; ++nt){
    if (nt < 15){
      const short* kn = kb + (size_t)(nt+1)*768*8;
      const short* vn = vb + (size_t)(nt+1)*768*8;
#pragma unroll
      for (int it = 0; it < 3; ++it){
        int c = it*256 + tid;
        gload16(kn + (size_t)c*8, (char*)&Klds[cur^1][0] + (size_t)c*16);
        gload16(vn + (size_t)c*8, (char*)&Vlds[cur^1][0] + (size_t)c*16);
      }
    }

    f32x4 sa[2][4];
    __builtin_amdgcn_s_setprio(1);
#pragma unroll
    for (int ct = 0; ct < 4; ++ct){
      bf16x8 kf[3];
#pragma unroll
      for (int t = 0; t < 3; ++t)
        kf[t] = *reinterpret_cast<const bf16x8*>(&Klds[cur][((t*4+lg)*64 + ct*16 + l15)*8]);
#pragma unroll
      for (int qm = 0; qm < 2; ++qm){
        f32x4 a = {};
#pragma unroll
        for (int t = 0; t < 3; ++t)
          a = __builtin_amdgcn_mfma_f32_16x16x32_bf16(qf[qm][t], kf[t], a, 0, 0, 0);
        sa[qm][ct] = a;
      }
    }
    __builtin_amdgcn_s_setprio(0);

    float pmax[2][4];
    bool need = false;
#pragma unroll
    for (int qm = 0; qm < 2; ++qm)
#pragma unroll
      for (int r = 0; r < 4; ++r){
        pmax[qm][r] = fmaxf(fmaxf(sa[qm][0][r], sa[qm][1][r]),
                            fmaxf(sa[qm][2][r], sa[qm][3][r]));
        need = need || (pmax[qm][r] > mrun[qm][r] + THRRAW);
      }
    if (__any(need)){
#pragma unroll
      for (int qm = 0; qm < 2; ++qm)
#pragma unroll
        for (int r = 0; r < 4; ++r){
          float mx = pmax[qm][r];
#pragma unroll
          for (int d = 1; d < 16; d <<= 1) mx = fmaxf(mx, __shfl_xor(mx, d, 64));
          float mnew = fmaxf(mrun[qm][r], mx);
          float al = exp2f((mrun[qm][r] - mnew)*C2);
          lrun[qm][r] *= al;
#pragma unroll
          for (int dt = 0; dt < 6; ++dt) Oacc[qm][dt][r] *= al;
          mrun[qm][r] = mnew;
        }
    }

#pragma unroll
    for (int qm = 0; qm < 2; ++qm)
#pragma unroll
      for (int r = 0; r < 4; ++r){
        float mc = mrun[qm][r]*C2;
        float s = 0.f;
#pragma unroll
        for (int ct = 0; ct < 4; ++ct){
          float p = exp2f(fmaf(sa[qm][ct][r], C2, -mc));
          sa[qm][ct][r] = p; s += p;
        }
        lrun[qm][r] += s;
      }

    bf16x8 vf[2][6];
#pragma unroll
    for (int ct = 0; ct < 4; ++ct)
#pragma unroll
      for (int r = 0; r < 4; ++r)
        Plds[w][(lg*4 + r)*72 + ct*16 + l15] = f2bf(sa[0][ct][r]);
    __builtin_amdgcn_s_setprio(1);
#pragma unroll
    for (int ks = 0; ks < 2; ++ks){
      bf16x8 pa = *reinterpret_cast<const bf16x8*>(&Plds[w][l15*72 + ks*32 + lg*8]);
#pragma unroll
      for (int dt = 0; dt < 6; ++dt){
        vf[ks][dt] = *reinterpret_cast<const bf16x8*>(&Vlds[cur][((ks*4+lg)*96 + dt*16 + l15)*8]);
        Oacc[0][dt] = __builtin_amdgcn_mfma_f32_16x16x32_bf16(pa, vf[ks][dt], Oacc[0][dt], 0, 0, 0);
      }
    }
    __builtin_amdgcn_s_setprio(0);
#pragma unroll
    for (int ct = 0; ct < 4; ++ct)
#pragma unroll
      for (int r = 0; r < 4; ++r)
        Plds[w][(lg*4 + r)*72 + ct*16 + l15] = f2bf(sa[1][ct][r]);
    __builtin_amdgcn_s_setprio(1);
#pragma unroll
    for (int ks = 0; ks < 2; ++ks){
      bf16x8 pa = *reinterpret_cast<const bf16x8*>(&Plds[w][l15*72 + ks*32 + lg*8]);
#pragma unroll
      for (int dt = 0; dt < 6; ++dt)
        Oacc[1][dt] = __builtin_amdgcn_mfma_f32_16x16x32_bf16(pa, vf[ks][dt], Oacc[1][dt], 0, 0, 0);
    }
    __builtin_amdgcn_s_setprio(0);

    __syncthreads();
    cur ^= 1;
  }

  // epilogue: reduce l once; fold gate so o = gate * softmax(QK)V
#pragma unroll
  for (int qm = 0; qm < 2; ++qm)
#pragma unroll
    for (int r = 0; r < 4; ++r){
      float l = lrun[qm][r];
#pragma unroll
      for (int d = 1; d < 16; d <<= 1) l += __shfl_xor(l, d, 64);
      int token = tok0 + qm*16 + lg*4 + r;
      float inv = gates[token*HEADS + h] / l;
#pragma unroll
      for (int dt = 0; dt < 6; ++dt)
        o[(size_t)token*DIM + h*HD + dt*16 + l15] = f2bf(Oacc[qm][dt][r]*inv);
    }
}

// ---------------- launch ----------------
extern "C" void kernel_launch(void* const* d_in, const int* in_sizes, int n_in,
                              void* d_out, int out_size, void* d_ws, size_t ws_size,
                              hipStream_t stream) {
  (void)in_sizes; (void)n_in; (void)out_size; (void)ws_size;
  const float* x    = (const float*)d_in[0];
  const float* Wg   = (const float*)d_in[1];
  const float* W1   = (const float*)d_in[2];
  const float* W2   = (const float*)d_in[3];
  const float* Wkv  = (const float*)d_in[4];
  const float* bkv  = (const float*)d_in[5];
  const int*   task = (const int*)d_in[6];

  char* ws = (char*)d_ws;
  short* xb    = (short*)(ws + OFF_XB);
  short* o     = (short*)(ws + OFF_XB);    // alias: xb dead after GEMM1
  short* Bt1   = (short*)(ws + OFF_BT1);
  short* W2t   = (short*)(ws + OFF_W2T);
  short* Kp    = (short*)(ws + OFF_K);
  short* Vp    = (short*)(ws + OFF_VT);
  float* gates = (float*)(ws + OFF_GATE);
  int*   topi  = (int*)(ws + OFF_TOPI);
  float* aux   = (float*)(ws + OFF_AUX);
  short* allq  = (short*)(ws + OFF_ALLQ);
  float* out   = (float*)d_out;

  hipMemsetAsync(aux, 0, 256, stream);
  prep_kernel  <<<20736, 256, 0, stream>>>(x, W1, Wkv, W2, xb, Bt1, W2t);
  gating_kernel<<<TOK/16, 256, 0, stream>>>(x, Wg, task, topi, gates, aux);
  aux_final    <<<1, 64, 0, stream>>>(aux, out + (size_t)TOK*DIM);
  // all_q (+ kv columns): [8192,768] x [768,2560]
  gemm_bt<true><<<dim3(NQP/128, TOK/128), 256, 0, stream>>>(xb, Bt1, allq, TOK, NQP, DIM);
  split_kv_tile<<<128, 256, 0, stream>>>(allq, bkv, Kp, Vp);
  attn_fwd     <<<dim3(8, 64), 256, 0, stream>>>(allq, topi, gates, Kp, Vp, o);
  // out = mixed(gated o) @ W2 : [8192,2304] x [2304,768], A built in-kernel
  gemm2_fused  <<<dim3(DIM/64, TOK/128), 256, 0, stream>>>(o, topi, W2t, out);
}

// Round 7
// 223.377 us; speedup vs baseline: 1.1426x; 1.0008x over previous
//
#include <hip/hip_runtime.h>
#include <hip/hip_bf16.h>
#include <stdint.h>

#define DEVFN static __device__ __forceinline__

typedef __attribute__((ext_vector_type(8))) short bf16x8;
typedef __attribute__((ext_vector_type(4))) short s16x4;
typedef __attribute__((ext_vector_type(4))) float f32x4;

static constexpr int TOK = 8192;       // B*N
static constexpr int DIM = 768;
static constexpr int HEADS = 8;
static constexpr int HD = 96;
static constexpr int EXPERTS = 24;
static constexpr int NQ = 2304;        // EXPERTS*HD
static constexpr int NQP = 2560;       // NQ + 192 (kv) + 64 (zero pad)
static constexpr float C2 = 0.14724484f;   // HD^-0.5 * log2(e)
static constexpr float THRRAW = 78.0f;     // defer-max threshold, raw-score units

// ---- workspace layout (bytes) ----
static constexpr size_t OFF_XB   = 0;          // x bf16 [8192][768]   (o aliases)
static constexpr size_t OFF_BT1  = 12582912;   // Bt1 bf16 [2560][768]
static constexpr size_t OFF_W2T  = 16515072;   // W2t bf16 [768][2304]
static constexpr size_t OFF_K    = 20054016;   // Kp packed bf16 [128 tiles][12][64][8]
static constexpr size_t OFF_VT   = 21626880;   // Vp packed bf16 [128 tiles][8][96][8]
static constexpr size_t OFF_GATE = 23199744;   // gates f32 [8192][8]
static constexpr size_t OFF_TOPI = 23461888;   // topi i32 [8192][8]
static constexpr size_t OFF_AUX  = 23724032;   // me[24], fe[24], z
static constexpr size_t OFF_ALLQ = 23724288;   // allq bf16 [8192][2560]

DEVFN short f2bf(float f){
  __hip_bfloat16 h = __float2bfloat16(f);
  return __builtin_bit_cast(short, h);
}
DEVFN float bf2f(short u){
  return __bfloat162float(__builtin_bit_cast(__hip_bfloat16, u));
}

DEVFN void gload16(const void* g, void* l){
  auto gp = reinterpret_cast<__attribute__((address_space(1))) unsigned int*>(
      reinterpret_cast<uintptr_t>(g));
  auto lp = reinterpret_cast<__attribute__((address_space(3))) unsigned int*>(
      reinterpret_cast<uintptr_t>(l));
  __builtin_amdgcn_global_load_lds(gp, lp, 16, 0, 0);
}

// ---------------- fused prep: casts / transposes ----------------
__global__ __launch_bounds__(256) void prep_kernel(const float* __restrict__ x,
                                                   const float* __restrict__ W1,
                                                   const float* __restrict__ Wkv,
                                                   const float* __restrict__ W2,
                                                   short* __restrict__ xb,
                                                   short* __restrict__ Bt1,
                                                   short* __restrict__ W2t){
  int bid = blockIdx.x, tid = threadIdx.x;
  if (bid < 6144){                                    // cast x -> bf16
    int i = bid*256 + tid;
    float4 v = ((const float4*)x)[i];
    s16x4 o4;
    o4[0] = f2bf(v.x); o4[1] = f2bf(v.y); o4[2] = f2bf(v.z); o4[3] = f2bf(v.w);
    *reinterpret_cast<s16x4*>(xb + (size_t)i*4) = o4;
  } else if (bid < 13056){                            // W1 -> Bt1[n][k]
    int i = (bid-6144)*256 + tid;                     // 24*768*96
    int e = i / (DIM*HD);
    int rem = i - e*(DIM*HD);
    int d = rem / HD, hh = rem - d*HD;
    Bt1[(size_t)(e*HD + hh)*DIM + d] = f2bf(W1[i]);
  } else if (bid < 13632){                            // Wkv -> Bt1 kv rows
    int i = (bid-13056)*256 + tid;                    // 768*192
    int d = i / 192, j = i - d*192;
    Bt1[(size_t)(NQ + j)*DIM + d] = f2bf(Wkv[i]);
  } else if (bid < 13824){                            // zero pad rows
    int i = (bid-13632)*256 + tid;                    // 64*768
    Bt1[(size_t)(NQ + 192)*DIM + i] = 0;
  } else {                                            // W2 -> W2t[c][e*96+h]
    int i = (bid-13824)*256 + tid;                    // 24*96*768
    int e = i / (HD*DIM);
    int rem = i - e*(HD*DIM);
    int hh = rem / DIM, c = rem - hh*DIM;
    W2t[(size_t)c*NQ + e*HD + hh] = f2bf(W2[i]);
  }
}

// ---------------- gating v3: LDS-staged W, transaction-clean, f32 ----------------
// 512 blocks x 16 tokens. Wave = 4 tokens (16-lane groups). W staged per K-half
// into [384][25]-padded LDS (pad-25: lanes j=0..15 at row stride 2 hit 16 distinct
// banks; token groups broadcast). x read once, coalesced float2. Top-8 serial per
// token, redundant across the 16 lanes of its group (no divergence).
__global__ __launch_bounds__(256) void gating_kernel(const float* __restrict__ x,
                                                     const float* __restrict__ Wg,
                                                     const int* __restrict__ task,
                                                     int* __restrict__ topi,
                                                     float* __restrict__ gates,
                                                     float* __restrict__ auxbuf){
  __shared__ float Wl[384*25];        // 38400 B
  __shared__ float part[16][25];      // K-half-0 logits
  __shared__ float lme[EXPERTS];
  __shared__ float lfr[EXPERTS];
  __shared__ float lz;
  int tid = threadIdx.x;
  int lane = tid & 63, w = tid >> 6;
  int g = lane >> 4, j = lane & 15;
  if (tid < EXPERTS){ lme[tid] = 0.f; lfr[tid] = 0.f; }
  if (tid == 0) lz = 0.f;

  int tokloc = w*4 + g;
  int token = blockIdx.x*16 + tokloc;
  const float* Wt = Wg + (size_t)task[0]*(DIM*EXPERTS);
  const float* xr = x + (size_t)token*DIM;

  float acc[EXPERTS];
#pragma unroll
  for (int e = 0; e < EXPERTS; ++e) acc[e] = 0.f;

  for (int kh = 0; kh < 2; ++kh){
    __syncthreads();                 // waves done with previous Wl (and lme init)
    // stage K-half: rows [kh*384, kh*384+384) -> Wl[d][25], coalesced float4 reads
    for (int idx = tid; idx < 384*6; idx += 256){
      int d = idx / 6, q = idx - d*6;
      float4 w4 = *reinterpret_cast<const float4*>(Wt + (size_t)(kh*384 + d)*EXPERTS + q*4);
      float* dst = &Wl[d*25 + q*4];
      dst[0] = w4.x; dst[1] = w4.y; dst[2] = w4.z; dst[3] = w4.w;
    }
    __syncthreads();

#pragma unroll 2
    for (int i = 0; i < 12; ++i){
      int d = i*32 + j*2;
      float2 xv = *reinterpret_cast<const float2*>(xr + kh*384 + d);
      const float* w0 = &Wl[d*25];
#pragma unroll
      for (int e = 0; e < EXPERTS; ++e)
        acc[e] = fmaf(xv.x, w0[e], fmaf(xv.y, w0[25 + e], acc[e]));
    }

    if (kh == 0){
      // reduce K-half-0 within the 16-lane group, stash, reset
#pragma unroll
      for (int e = 0; e < EXPERTS; ++e){
        float v = acc[e];
#pragma unroll
        for (int m = 1; m < 16; m <<= 1) v += __shfl_xor(v, m, 64);
        acc[e] = v;
      }
      part[tokloc][j] = acc[j];
      if (j < 8) part[tokloc][16 + j] = acc[16 + j];
#pragma unroll
      for (int e = 0; e < EXPERTS; ++e) acc[e] = 0.f;
    }
  }
  // final reduce + add stashed partial -> full logits in every lane of the group
#pragma unroll
  for (int e = 0; e < EXPERTS; ++e){
    float v = acc[e];
#pragma unroll
    for (int m = 1; m < 16; m <<= 1) v += __shfl_xor(v, m, 64);
    acc[e] = v + part[tokloc][e];
  }

  // top-8 (strict >, lowest index wins ties -> matches lax.top_k)
  float mx = acc[0];
#pragma unroll
  for (int e = 1; e < EXPERTS; ++e) mx = fmaxf(mx, acc[e]);
  unsigned selm = 0; int sel[8]; float sg[8];
#pragma unroll
  for (int t = 0; t < 8; ++t){
    float best = -3.0e38f; int bi = 0;
#pragma unroll
    for (int e = 0; e < EXPERTS; ++e){
      bool ok = !((selm>>e)&1u) && (acc[e] > best);
      best = ok ? acc[e] : best;
      bi   = ok ? e      : bi;
    }
    selm |= (1u<<bi); sel[t] = bi; sg[t] = best;
  }

  float S = 0.f;
#pragma unroll
  for (int e = 0; e < EXPERTS; ++e) S += __expf(acc[e] - mx);
  float lse = mx + __logf(S);
  float Sinv = 1.f/S;
  float gsum = 0.f;
#pragma unroll
  for (int t = 0; t < 8; ++t){ sg[t] = __expf(sg[t] - mx)*Sinv; gsum += sg[t]; }
  float dinv = 1.f/(gsum + 1e-6f);

  if (j == 0){
#pragma unroll
    for (int t = 0; t < 8; ++t){
      topi[token*HEADS + t]  = sel[t];
      gates[token*HEADS + t] = sg[t]*dinv;
    }
#pragma unroll
    for (int e = 0; e < EXPERTS; ++e) atomicAdd(&lme[e], __expf(acc[e] - mx)*Sinv);
#pragma unroll
    for (int t = 0; t < 8; ++t) atomicAdd(&lfr[sel[t]], 1.f);
    atomicAdd(&lz, lse*lse);
  }
  __syncthreads();
  if (tid < EXPERTS) atomicAdd(&auxbuf[tid], lme[tid]);
  else if (tid >= 32 && tid < 32+EXPERTS) atomicAdd(&auxbuf[EXPERTS + tid-32], lfr[tid-32]);
  else if (tid == 63) atomicAdd(&auxbuf[2*EXPERTS], lz);
}

__global__ void aux_final(const float* __restrict__ auxbuf, float* __restrict__ outa){
  if (threadIdx.x != 0 || blockIdx.x != 0) return;
  float ms = 0.f, fs = 0.f;
  for (int e=0;e<EXPERTS;++e){ ms += auxbuf[e]; fs += auxbuf[EXPERTS+e]; }
  float sw = 0.f;
  for (int e=0;e<EXPERTS;++e) sw += (auxbuf[e]/ms)*(auxbuf[EXPERTS+e]/fs);
  sw *= (float)EXPERTS;
  float z = auxbuf[2*EXPERTS] / (float)TOK;
  outa[0] = 0.1f*sw + 0.001f*z;
}

// ---------------- bf16 MFMA GEMM: 128x128 tile, XCD swizzle, T2 LDS swizzle ----------------
template<bool OUT_BF16>
__global__ __launch_bounds__(256) void gemm_bt(const short* __restrict__ A,
                                               const short* __restrict__ Bt,
                                               void* __restrict__ Cout,
                                               int M, int N, int K){
  __shared__ short As[128*64];
  __shared__ short Bs[128*64];
  int nwg = gridDim.x*gridDim.y;
  int orig = blockIdx.y*gridDim.x + blockIdx.x;
  int cpx = nwg >> 3;
  int swz = (orig & 7)*cpx + (orig >> 3);   // requires nwg % 8 == 0
  int bx = swz % gridDim.x, by = swz / gridDim.x;

  int tid = threadIdx.x;
  int lane = tid & 63, w = tid >> 6;
  int wr = w >> 1, wc = w & 1;
  int l15 = lane & 15, lg = lane >> 4;
  int m0 = by * 128, n0 = bx * 128;

  f32x4 acc[4][4] = {};

  for (int k0 = 0; k0 < K; k0 += 64){
#pragma unroll
    for (int it = 0; it < 4; ++it){
      int c = it*256 + tid;
      int row = c >> 3, cc = c & 7;
      int csrc = cc ^ (row & 7);            // pre-swizzled source chunk
      gload16(A  + (size_t)(m0+row)*K + k0 + csrc*8, (char*)As + (size_t)c*16);
      gload16(Bt + (size_t)(n0+row)*K + k0 + csrc*8, (char*)Bs + (size_t)c*16);
    }
    __syncthreads();
#pragma unroll
    for (int kk = 0; kk < 2; ++kk){
      bf16x8 af[4], bfr[4];
      int jp = (kk*4 + lg) ^ (l15 & 7);     // phys chunk for logical kk*4+lg
#pragma unroll
      for (int m = 0; m < 4; ++m)
        af[m] = *reinterpret_cast<const bf16x8*>(&As[(wr*64 + m*16 + l15)*64 + jp*8]);
#pragma unroll
      for (int n = 0; n < 4; ++n)
        bfr[n] = *reinterpret_cast<const bf16x8*>(&Bs[(wc*64 + n*16 + l15)*64 + jp*8]);
#pragma unroll
      for (int m = 0; m < 4; ++m)
#pragma unroll
        for (int n = 0; n < 4; ++n)
          acc[m][n] = __builtin_amdgcn_mfma_f32_16x16x32_bf16(af[m], bfr[n], acc[m][n], 0, 0, 0);
    }
    __syncthreads();
  }
#pragma unroll
  for (int m = 0; m < 4; ++m)
#pragma unroll
    for (int n = 0; n < 4; ++n){
      int rbase = m0 + wr*64 + m*16 + lg*4;
      int col   = n0 + wc*64 + n*16 + l15;
#pragma unroll
      for (int r = 0; r < 4; ++r){
        float v = acc[m][n][r];
        size_t idx = (size_t)(rbase + r)*N + col;
        if constexpr (OUT_BF16) ((short*)Cout)[idx] = f2bf(v);
        else                    ((float*)Cout)[idx] = v;
      }
    }
}

// ---------------- GEMM2 fused: dbuf LDS + T14 async gather pipeline ----------------
// out = mixed(gated o, topi) @ W2. A gathered to regs early, ds_written late;
// B prefetched via gload_lds across the single per-iter barrier. BK=64.
__global__ __launch_bounds__(256) void gemm2_fused(const short* __restrict__ o,
                                                   const int* __restrict__ topi,
                                                   const short* __restrict__ W2t,
                                                   float* __restrict__ out){
  __shared__ short As[2][128*64];
  __shared__ short Bs[2][64*64];
  __shared__ signed char hmap[128][24];
  int nwg = gridDim.x*gridDim.y;
  int orig = blockIdx.y*gridDim.x + blockIdx.x;
  int cpx = nwg >> 3;
  int swz = (orig & 7)*cpx + (orig >> 3);   // 12*64=768, %8==0
  int bx = swz % gridDim.x, by = swz / gridDim.x;

  int tid = threadIdx.x;
  int lane = tid & 63, w = tid >> 6;
  int l15 = lane & 15, lg = lane >> 4;
  int m0 = by * 128, n0 = bx * 64;

  int* hm32 = (int*)&hmap[0][0];
  for (int i = tid; i < 768; i += 256) hm32[i] = -1;   // all bytes 0xFF
  __syncthreads();
  for (int i = tid; i < 128*8; i += 256){
    int row = i >> 3, hh = i & 7;
    int e = topi[(size_t)(m0+row)*HEADS + hh];
    hmap[row][e] = (signed char)hh;
  }
  __syncthreads();

  // per-thread A-gather invariants: 4 chunks (row, cc)
  int arow[4], accv[4];
  size_t arbase[4];
#pragma unroll
  for (int it = 0; it < 4; ++it){
    int c = it*256 + tid;
    arow[it] = c >> 3; accv[it] = c & 7;
    arbase[it] = (size_t)(m0 + arow[it])*DIM;
  }

  f32x4 acc[2][4] = {};
  bf16x8 areg[4];

  // ---- staging helpers (inline) ----
#define STAGE_A(kt, dst)                                                     \
  {                                                                          \
    _Pragma("unroll")                                                        \
    for (int it = 0; it < 4; ++it){                                          \
      unsigned kc = (unsigned)((kt)*8 + accv[it]);                           \
      unsigned e = kc / 12u;                                                 \
      unsigned dc = kc - e*12u;                                              \
      int hh = hmap[arow[it]][e];                                            \
      bf16x8 av = {};                                                        \
      if (hh >= 0)                                                           \
        av = *reinterpret_cast<const bf16x8*>(o + arbase[it] + hh*HD + dc*8);\
      dst[it] = av;                                                          \
    }                                                                        \
  }
#define WRITE_A(buf, src)                                                    \
  {                                                                          \
    _Pragma("unroll")                                                        \
    for (int it = 0; it < 4; ++it)                                           \
      *reinterpret_cast<bf16x8*>(                                            \
        &As[buf][arow[it]*64 + ((accv[it] ^ (arow[it] & 7)))*8]) = src[it];  \
  }
#define STAGE_B(kt, buf)                                                     \
  {                                                                          \
    _Pragma("unroll")                                                        \
    for (int it = 0; it < 2; ++it){                                          \
      int c = it*256 + tid;                                                  \
      int row = c >> 3, cc = c & 7;                                          \
      int csrc = cc ^ (row & 7);                                             \
      gload16(W2t + (size_t)(n0+row)*NQ + (kt)*64 + csrc*8,                  \
              (char*)&Bs[buf][0] + (size_t)c*16);                            \
    }                                                                        \
  }

  // prologue
  STAGE_A(0, areg);
  STAGE_B(0, 0);
  WRITE_A(0, areg);
  __syncthreads();

  for (int kt = 0; kt < 36; ++kt){
    int buf = kt & 1;
    bf16x8 anext[4];
    if (kt < 35){
      STAGE_A(kt+1, anext);       // global loads in flight under MFMA
      STAGE_B(kt+1, buf^1);       // gload_lds in flight across barrier
    }
#pragma unroll
    for (int kk = 0; kk < 2; ++kk){
      int jp = (kk*4 + lg) ^ (l15 & 7);
      bf16x8 af[2], bfr[4];
#pragma unroll
      for (int m = 0; m < 2; ++m)
        af[m] = *reinterpret_cast<const bf16x8*>(&As[buf][(w*32 + m*16 + l15)*64 + jp*8]);
#pragma unroll
      for (int n = 0; n < 4; ++n)
        bfr[n] = *reinterpret_cast<const bf16x8*>(&Bs[buf][(n*16 + l15)*64 + jp*8]);
#pragma unroll
      for (int m = 0; m < 2; ++m)
#pragma unroll
        for (int n = 0; n < 4; ++n)
          acc[m][n] = __builtin_amdgcn_mfma_f32_16x16x32_bf16(af[m], bfr[n], acc[m][n], 0, 0, 0);
    }
    if (kt < 35) WRITE_A(buf^1, anext);
    __syncthreads();
  }
#undef STAGE_A
#undef WRITE_A
#undef STAGE_B

#pragma unroll
  for (int m = 0; m < 2; ++m)
#pragma unroll
    for (int n = 0; n < 4; ++n){
      int rbase = m0 + w*32 + m*16 + lg*4;
      int col   = n0 + n*16 + l15;
#pragma unroll
      for (int r = 0; r < 4; ++r)
        out[(size_t)(rbase + r)*DIM + col] = acc[m][n][r];
    }
}

// ---------------- split kv: bias + repack into fragment-chunk order ----------------
__global__ __launch_bounds__(256) void split_kv_tile(const short* __restrict__ allq,
                                                     const float* __restrict__ bkv,
                                                     short* __restrict__ Kp,
                                                     short* __restrict__ Vp){
  __shared__ short kv[64*192];
  int bt = blockIdx.x;                 // b*16 + nt
  int b = bt >> 4;
  int tid = threadIdx.x;
#pragma unroll
  for (int it = 0; it < 6; ++it){
    int c = it*256 + tid;              // 1536 chunks of 16B
    int j = c / 24, cc = c - j*24;
    int token = b*1024 + (bt & 15)*64 + j;
    gload16(allq + (size_t)token*NQP + NQ + cc*8, (char*)kv + (size_t)c*16);
  }
  __syncthreads();
#pragma unroll
  for (int it = 0; it < 3; ++it){
    int c = it*256 + tid;              // 768 K chunks
    int kc = c >> 6, j = c & 63;
    bf16x8 v = *reinterpret_cast<const bf16x8*>(&kv[j*192 + kc*8]);
    bf16x8 o8;
#pragma unroll
    for (int e = 0; e < 8; ++e) o8[e] = f2bf(bf2f(v[e]) + bkv[kc*8 + e]);
    *reinterpret_cast<bf16x8*>(Kp + ((size_t)bt*768 + c)*8) = o8;
  }
#pragma unroll
  for (int it = 0; it < 3; ++it){
    int c = it*256 + tid;              // 768 V chunks
    int kc = c / 96, hd = c - kc*96;
    float bias = bkv[96 + hd];
    bf16x8 o8;
#pragma unroll
    for (int e = 0; e < 8; ++e) o8[e] = f2bf(bf2f(kv[(kc*8 + e)*192 + 96 + hd]) + bias);
    *reinterpret_cast<bf16x8*>(Vp + ((size_t)bt*768 + c)*8) = o8;
  }
}

// ---------------- flash attention: 32 q-rows/wave, dbuf staging, lazy softmax, gate-folded ----------------
__global__ __launch_bounds__(256, 2) void attn_fwd(const short* __restrict__ allq,
                                                   const int* __restrict__ topi,
                                                   const float* __restrict__ gates,
                                                   const short* __restrict__ Kp,
                                                   const short* __restrict__ Vp,
                                                   short* __restrict__ o){
  __shared__ short Klds[2][768*8];
  __shared__ short Vlds[2][768*8];
  __shared__ short Plds[4][16*72];
  int qt = blockIdx.x, bh = blockIdx.y;        // qt in [0,8): 128 q-rows per block
  int b = bh >> 3, h = bh & 7;
  int tid = threadIdx.x;
  int lane = tid & 63, w = tid >> 6;
  int l15 = lane & 15, lg = lane >> 4;

  bf16x8 qf[2][3];
  int tok0 = b*1024 + qt*128 + w*32;
#pragma unroll
  for (int qm = 0; qm < 2; ++qm){
    int token = tok0 + qm*16 + l15;
    int qe = topi[token*HEADS + h];
    const short* qp = allq + (size_t)token*NQP + qe*HD;
#pragma unroll
    for (int t = 0; t < 3; ++t)
      qf[qm][t] = *reinterpret_cast<const bf16x8*>(qp + t*32 + lg*8);
  }

  f32x4 Oacc[2][6] = {};
  float mrun[2][4], lrun[2][4];
#pragma unroll
  for (int qm = 0; qm < 2; ++qm)
#pragma unroll
    for (int r = 0; r < 4; ++r){ mrun[qm][r] = -1.0e30f; lrun[qm][r] = 0.f; }

  const short* kb = Kp + (size_t)b*16*768*8;
  const short* vb = Vp + (size_t)b*16*768*8;

#pragma unroll
  for (int it = 0; it < 3; ++it){
    int c = it*256 + tid;
    gload16(kb + (size_t)c*8, (char*)&Klds[0][0] + (size_t)c*16);
    gload16(vb + (size_t)c*8, (char*)&Vlds[0][0] + (size_t)c*16);
  }
  __syncthreads();

  int cur = 0;
  for (int nt = 0; nt < 16; ++nt){
    if (nt < 15){
      const short* kn = kb + (size_t)(nt+1)*768*8;
      const short* vn = vb + (size_t)(nt+1)*768*8;
#pragma unroll
      for (int it = 0; it < 3; ++it){
        int c = it*256 + tid;
        gload16(kn + (size_t)c*8, (char*)&Klds[cur^1][0] + (size_t)c*16);
        gload16(vn + (size_t)c*8, (char*)&Vlds[cur^1][0] + (size_t)c*16);
      }
    }

    f32x4 sa[2][4];
    __builtin_amdgcn_s_setprio(1);
#pragma unroll
    for (int ct = 0; ct < 4; ++ct){
      bf16x8 kf[3];
#pragma unroll
      for (int t = 0; t < 3; ++t)
        kf[t] = *reinterpret_cast<const bf16x8*>(&Klds[cur][((t*4+lg)*64 + ct*16 + l15)*8]);
#pragma unroll
      for (int qm = 0; qm < 2; ++qm){
        f32x4 a = {};
#pragma unroll
        for (int t = 0; t < 3; ++t)
          a = __builtin_amdgcn_mfma_f32_16x16x32_bf16(qf[qm][t], kf[t], a, 0, 0, 0);
        sa[qm][ct] = a;
      }
    }
    __builtin_amdgcn_s_setprio(0);

    float pmax[2][4];
    bool need = false;
#pragma unroll
    for (int qm = 0; qm < 2; ++qm)
#pragma unroll
      for (int r = 0; r < 4; ++r){
        pmax[qm][r] = fmaxf(fmaxf(sa[qm][0][r], sa[qm][1][r]),
                            fmaxf(sa[qm][2][r], sa[qm][3][r]));
        need = need || (pmax[qm][r] > mrun[qm][r] + THRRAW);
      }
    if (__any(need)){
#pragma unroll
      for (int qm = 0; qm < 2; ++qm)
#pragma unroll
        for (int r = 0; r < 4; ++r){
          float mx = pmax[qm][r];
#pragma unroll
          for (int d = 1; d < 16; d <<= 1) mx = fmaxf(mx, __shfl_xor(mx, d, 64));
          float mnew = fmaxf(mrun[qm][r], mx);
          float al = exp2f((mrun[qm][r] - mnew)*C2);
          lrun[qm][r] *= al;
#pragma unroll
          for (int dt = 0; dt < 6; ++dt) Oacc[qm][dt][r] *= al;
          mrun[qm][r] = mnew;
        }
    }

#pragma unroll
    for (int qm = 0; qm < 2; ++qm)
#pragma unroll
      for (int r = 0; r < 4; ++r){
        float mc = mrun[qm][r]*C2;
        float s = 0.f;
#pragma unroll
        for (int ct = 0; ct < 4; ++ct){
          float p = exp2f(fmaf(sa[qm][ct][r], C2, -mc));
          sa[qm][ct][r] = p; s += p;
        }
        lrun[qm][r] += s;
      }

    bf16x8 vf[2][6];
#pragma unroll
    for (int ct = 0; ct < 4; ++ct)
#pragma unroll
      for (int r = 0; r < 4; ++r)
        Plds[w][(lg*4 + r)*72 + ct*16 + l15] = f2bf(sa[0][ct][r]);
    __builtin_amdgcn_s_setprio(1);
#pragma unroll
    for (int ks = 0; ks < 2; ++ks){
      bf16x8 pa = *reinterpret_cast<const bf16x8*>(&Plds[w][l15*72 + ks*32 + lg*8]);
#pragma unroll
      for (int dt = 0; dt < 6; ++dt){
        vf[ks][dt] = *reinterpret_cast<const bf16x8*>(&Vlds[cur][((ks*4+lg)*96 + dt*16 + l15)*8]);
        Oacc[0][dt] = __builtin_amdgcn_mfma_f32_16x16x32_bf16(pa, vf[ks][dt], Oacc[0][dt], 0, 0, 0);
      }
    }
    __builtin_amdgcn_s_setprio(0);
#pragma unroll
    for (int ct = 0; ct < 4; ++ct)
#pragma unroll
      for (int r = 0; r < 4; ++r)
        Plds[w][(lg*4 + r)*72 + ct*16 + l15] = f2bf(sa[1][ct][r]);
    __builtin_amdgcn_s_setprio(1);
#pragma unroll
    for (int ks = 0; ks < 2; ++ks){
      bf16x8 pa = *reinterpret_cast<const bf16x8*>(&Plds[w][l15*72 + ks*32 + lg*8]);
#pragma unroll
      for (int dt = 0; dt < 6; ++dt)
        Oacc[1][dt] = __builtin_amdgcn_mfma_f32_16x16x32_bf16(pa, vf[ks][dt], Oacc[1][dt], 0, 0, 0);
    }
    __builtin_amdgcn_s_setprio(0);

    __syncthreads();
    cur ^= 1;
  }

  // epilogue: reduce l once; fold gate so o = gate * softmax(QK)V
#pragma unroll
  for (int qm = 0; qm < 2; ++qm)
#pragma unroll
    for (int r = 0; r < 4; ++r){
      float l = lrun[qm][r];
#pragma unroll
      for (int d = 1; d < 16; d <<= 1) l += __shfl_xor(l, d, 64);
      int token = tok0 + qm*16 + lg*4 + r;
      float inv = gates[token*HEADS + h] / l;
#pragma unroll
      for (int dt = 0; dt < 6; ++dt)
        o[(size_t)token*DIM + h*HD + dt*16 + l15] = f2bf(Oacc[qm][dt][r]*inv);
    }
}

// ---------------- launch ----------------
extern "C" void kernel_launch(void* const* d_in, const int* in_sizes, int n_in,
                              void* d_out, int out_size, void* d_ws, size_t ws_size,
                              hipStream_t stream) {
  (void)in_sizes; (void)n_in; (void)out_size; (void)ws_size;
  const float* x    = (const float*)d_in[0];
  const float* Wg   = (const float*)d_in[1];
  const float* W1   = (const float*)d_in[2];
  const float* W2   = (const float*)d_in[3];
  const float* Wkv  = (const float*)d_in[4];
  const float* bkv  = (const float*)d_in[5];
  const int*   task = (const int*)d_in[6];

  char* ws = (char*)d_ws;
  short* xb    = (short*)(ws + OFF_XB);
  short* o     = (short*)(ws + OFF_XB);    // alias: xb dead after GEMM1
  short* Bt1   = (short*)(ws + OFF_BT1);
  short* W2t   = (short*)(ws + OFF_W2T);
  short* Kp    = (short*)(ws + OFF_K);
  short* Vp    = (short*)(ws + OFF_VT);
  float* gates = (float*)(ws + OFF_GATE);
  int*   topi  = (int*)(ws + OFF_TOPI);
  float* aux   = (float*)(ws + OFF_AUX);
  short* allq  = (short*)(ws + OFF_ALLQ);
  float* out   = (float*)d_out;

  hipMemsetAsync(aux, 0, 256, stream);
  prep_kernel  <<<20736, 256, 0, stream>>>(x, W1, Wkv, W2, xb, Bt1, W2t);
  gating_kernel<<<TOK/16, 256, 0, stream>>>(x, Wg, task, topi, gates, aux);
  aux_final    <<<1, 64, 0, stream>>>(aux, out + (size_t)TOK*DIM);
  // all_q (+ kv columns): [8192,768] x [768,2560]
  gemm_bt<true><<<dim3(NQP/128, TOK/128), 256, 0, stream>>>(xb, Bt1, allq, TOK, NQP, DIM);
  split_kv_tile<<<128, 256, 0, stream>>>(allq, bkv, Kp, Vp);
  attn_fwd     <<<dim3(8, 64), 256, 0, stream>>>(allq, topi, gates, Kp, Vp, o);
  // out = mixed(gated o) @ W2 : [8192,2304] x [2304,768], A built in-kernel
  gemm2_fused  <<<dim3(DIM/64, TOK/128), 256, 0, stream>>>(o, topi, W2t, out);
}